// Round 2
// baseline (981.796 us; speedup 1.0000x reference)
//
#include <hip/hip_runtime.h>

// ---------------------------------------------------------------------------
// ResBlock GNN layer on MI355X (gfx950). ALL tensors fp32 (reference dtypes).
//   h  = gelu(x @ W_ff1 + b)
//   h  = h + seg_sum(gelu(P[src]+Q[dst]+R_e+b_mp)) for each of 2 MP layers,
//        where P=h@W_a, Q=h@W_b, R=ef@W_c   (W_mp rows [0:256|256:512|512:576])
//   out = x + h @ W_ff2 + b
// GEMM core: bf16 MFMA 16x16x32 (inputs RNE-rounded to bf16; epilogue fp32).
// segment_sum: fp32 atomicAdd into Hacc (which already holds the residual h).
// ---------------------------------------------------------------------------

typedef __attribute__((ext_vector_type(8))) short short8;
typedef __attribute__((ext_vector_type(4))) float f32x4;

#define HD __device__ __forceinline__

HD unsigned short f2bf(float f) {
    unsigned int u = __float_as_uint(f);
    unsigned int r = (u + 0x7fffu + ((u >> 16) & 1u)) >> 16;  // RNE
    return (unsigned short)r;
}
HD float gelu_f(float x) {
    // tanh approximation (jax.nn.gelu default approximate=True)
    float t = tanhf(0.7978845608028654f * (x + 0.044715f * x * x * x));
    return 0.5f * x * (1.0f + t);
}

// ---------------------------------------------------------------------------
// Repack fp32 B [K,256] (row-major, from row `rowoff`) into bf16 MFMA B-frag
// order: Bp[((kb*16 + ntile)*64 + lane)*8 + j] = bf16(B[kb*32 + (lane>>4)*8 + j][ntile*16 + (lane&15)])
// ---------------------------------------------------------------------------
__global__ void repack_kernel(const float* __restrict__ B, int rowoff,
                              int K, unsigned short* __restrict__ Bp) {
    int i = blockIdx.x * 256 + threadIdx.x;
    if (i >= K * 256) return;
    int k = i >> 8, n = i & 255;
    int kb = k >> 5, kr = k & 31;
    int quad = kr >> 3, j = kr & 7;
    int lane = quad * 16 + (n & 15);
    int nt = n >> 4;
    Bp[((((kb * 16 + nt) * 64) + lane) << 3) + j] =
        f2bf(B[(size_t)(rowoff + k) * 256 + n]);
}

// ---------------------------------------------------------------------------
// LDS-free bf16 MFMA GEMM: C[M,256] = epilogue(A[M,K] @ B + bias).
// Block 256 thr (4 waves), tile 64 rows x 64 cols; wave w owns rows 16w..16w+15.
// grid = (ceil(M/64), 4). B pre-repacked (cache-resident, <=128 KB).
// A is fp32 (a_is_f32=1, converted on the fly) or bf16 (a_is_f32=0).
// Epilogue fp32: optional gelu, optional fp32 residual, writes bf16 and/or f32.
// ---------------------------------------------------------------------------
__global__ __launch_bounds__(256) void gemm_kernel(
    const void* __restrict__ Av, int a_is_f32, int M, int K,
    const unsigned short* __restrict__ Bp,
    const float* __restrict__ bias,   // nullable, [256] f32
    const float* __restrict__ resid,  // nullable, [M,256] f32
    unsigned short* __restrict__ Cb,  // nullable, [M,256] bf16
    float* __restrict__ Cf,           // nullable, [M,256] f32
    int do_gelu) {
    int lane = threadIdx.x & 63;
    int w = threadIdx.x >> 6;
    int row0 = blockIdx.x * 64 + w * 16;
    int n0 = blockIdx.y * 64;
    int m15 = lane & 15, quad = lane >> 4;

    int arow = row0 + m15;
    if (arow > M - 1) arow = M - 1;  // clamp loads; stores masked below

    f32x4 acc[4] = {{0.f, 0.f, 0.f, 0.f},
                    {0.f, 0.f, 0.f, 0.f},
                    {0.f, 0.f, 0.f, 0.f},
                    {0.f, 0.f, 0.f, 0.f}};

    const float* Af = (const float*)Av + (size_t)arow * K + quad * 8;
    const unsigned short* Ab = (const unsigned short*)Av + (size_t)arow * K + quad * 8;

    for (int kt = 0; kt < K; kt += 32) {
        short8 a;
        if (a_is_f32) {
            f32x4 lo = *(const f32x4*)(Af + kt);
            f32x4 hi = *(const f32x4*)(Af + kt + 4);
#pragma unroll
            for (int j = 0; j < 4; ++j) {
                a[j] = (short)f2bf(lo[j]);
                a[j + 4] = (short)f2bf(hi[j]);
            }
        } else {
            a = *(const short8*)(Ab + kt);
        }
        const unsigned short* bbase =
            Bp + ((((size_t)(kt >> 5) * 16 + (n0 >> 4)) * 64 + lane) << 3);
#pragma unroll
        for (int nt = 0; nt < 4; ++nt) {
            short8 b = *(const short8*)(bbase + nt * 64 * 8);
            acc[nt] = __builtin_amdgcn_mfma_f32_16x16x32_bf16(a, b, acc[nt], 0, 0, 0);
        }
    }

#pragma unroll
    for (int nt = 0; nt < 4; ++nt) {
        int col = n0 + nt * 16 + m15;
        float bv = bias ? bias[col] : 0.f;
#pragma unroll
        for (int r = 0; r < 4; ++r) {
            int row = row0 + quad * 4 + r;
            if (row < M) {
                float v = acc[nt][r] + bv;
                if (do_gelu) v = gelu_f(v);
                size_t idx = (size_t)row * 256 + col;
                if (resid) v += resid[idx];
                if (Cb) Cb[idx] = f2bf(v);
                if (Cf) Cf[idx] = v;
            }
        }
    }
}

// ---------------------------------------------------------------------------
// Edge kernel: m = gelu(P[src]+Q[dst]+R[e]+b); Hacc[dst] += m (fp32 atomics).
// Block = 256 threads = one channel each; grid-stride over edges.
// ---------------------------------------------------------------------------
__global__ __launch_bounds__(256) void edge_kernel(
    const float* __restrict__ P, const float* __restrict__ Q,
    const unsigned short* __restrict__ R, const float* __restrict__ bmp,
    const int* __restrict__ src, const int* __restrict__ dst,
    float* __restrict__ Hacc, int nE) {
    int c = threadIdx.x;
    float bias = bmp[c];
    for (int e = blockIdx.x; e < nE; e += gridDim.x) {
        int s = src[e];
        int d = dst[e];
        float v = P[(size_t)s * 256 + c] + Q[(size_t)d * 256 + c] +
                  __uint_as_float(((unsigned int)R[(size_t)e * 256 + c]) << 16) + bias;
        atomicAdd(&Hacc[(size_t)d * 256 + c], gelu_f(v));
    }
}

// Hacc (f32) -> h_bf (bf16) for the next stage's MFMA GEMMs.
__global__ void f2bf_kernel(const float* __restrict__ in,
                            unsigned short* __restrict__ out, int n) {
    int i = blockIdx.x * 256 + threadIdx.x;
    if (i < n) out[i] = f2bf(in[i]);
}

// ---------------------------------------------------------------------------
extern "C" void kernel_launch(void* const* d_in, const int* in_sizes, int n_in,
                              void* d_out, int out_size, void* d_ws, size_t ws_size,
                              hipStream_t stream) {
    const float* x     = (const float*)d_in[0];
    const int*   ei    = (const int*)d_in[1];
    const float* ef    = (const float*)d_in[2];
    const float* W_ff1 = (const float*)d_in[3];
    const float* b_ff1 = (const float*)d_in[4];
    const float* W_mp1 = (const float*)d_in[5];
    const float* b_mp1 = (const float*)d_in[6];
    const float* W_mp2 = (const float*)d_in[7];
    const float* b_mp2 = (const float*)d_in[8];
    const float* W_ff2 = (const float*)d_in[9];
    const float* b_ff2 = (const float*)d_in[10];

    const int N = in_sizes[0] / 256;  // 10000
    const int E = in_sizes[1] / 2;    // 320000
    const int* src = ei;
    const int* dst = ei + E;

    // ---- workspace carve (all offsets 256B-aligned) ----
    char* p = (char*)d_ws;
    unsigned short* h_bf = (unsigned short*)p;      p += (size_t)N * 256 * 2;   // 5.12 MB
    float* Pbuf = (float*)p;                        p += (size_t)N * 256 * 4;   // 10.24 MB
    float* Qbuf = (float*)p;                        p += (size_t)N * 256 * 4;
    float* Hacc = (float*)p;                        p += (size_t)N * 256 * 4;
    unsigned short* Bp = (unsigned short*)p;        p += 425984ull * 2;         // packed weights
    unsigned short* Rbuf = (unsigned short*)p;      // bf16 R chunks

    long long used = (long long)(p - (char*)d_ws);
    long long remain = (long long)ws_size - used;
    long long chunk = remain / 512;  // 256 bf16 per edge row
    chunk -= (chunk % 64);
    if (chunk > E) chunk = E;
    if (chunk < 64) chunk = 64;

    unsigned short* Bp_ff1 = Bp + 0;
    unsigned short* Bp_a1  = Bp + 65536;
    unsigned short* Bp_b1  = Bp + 131072;
    unsigned short* Bp_c1  = Bp + 196608;
    unsigned short* Bp_a2  = Bp + 212992;
    unsigned short* Bp_b2  = Bp + 278528;
    unsigned short* Bp_c2  = Bp + 344064;
    unsigned short* Bp_ff2 = Bp + 360448;

    // ---- repack weights (fp32 -> bf16 fragments) ----
    repack_kernel<<<256, 256, 0, stream>>>(W_ff1, 0, 256, Bp_ff1);
    repack_kernel<<<256, 256, 0, stream>>>(W_mp1, 0, 256, Bp_a1);
    repack_kernel<<<256, 256, 0, stream>>>(W_mp1, 256, 256, Bp_b1);
    repack_kernel<<<64, 256, 0, stream>>>(W_mp1, 512, 64, Bp_c1);
    repack_kernel<<<256, 256, 0, stream>>>(W_mp2, 0, 256, Bp_a2);
    repack_kernel<<<256, 256, 0, stream>>>(W_mp2, 256, 256, Bp_b2);
    repack_kernel<<<64, 256, 0, stream>>>(W_mp2, 512, 64, Bp_c2);
    repack_kernel<<<256, 256, 0, stream>>>(W_ff2, 0, 256, Bp_ff2);

    dim3 gN((N + 63) / 64, 4);

    // ---- FFN1: h = gelu(x@W_ff1 + b); h_bf for GEMMs, Hacc = residual base
    gemm_kernel<<<gN, 256, 0, stream>>>(x, 1, N, 256, Bp_ff1, b_ff1, nullptr,
                                        h_bf, Hacc, 1);

    const unsigned short* Bp_a[2] = {Bp_a1, Bp_a2};
    const unsigned short* Bp_b[2] = {Bp_b1, Bp_b2};
    const unsigned short* Bp_c[2] = {Bp_c1, Bp_c2};
    const float* bmp[2] = {b_mp1, b_mp2};

    for (int l = 0; l < 2; ++l) {
        gemm_kernel<<<gN, 256, 0, stream>>>(h_bf, 0, N, 256, Bp_a[l], nullptr,
                                            nullptr, nullptr, Pbuf, 0);
        gemm_kernel<<<gN, 256, 0, stream>>>(h_bf, 0, N, 256, Bp_b[l], nullptr,
                                            nullptr, nullptr, Qbuf, 0);
        for (long long off = 0; off < E; off += chunk) {
            int len = (int)((E - off < chunk) ? (E - off) : chunk);
            dim3 gR((len + 63) / 64, 4);
            gemm_kernel<<<gR, 256, 0, stream>>>(ef + off * 64, 1, len, 64, Bp_c[l],
                                                nullptr, nullptr, Rbuf, nullptr, 0);
            int nblk = len < 16384 ? len : 16384;
            edge_kernel<<<nblk, 256, 0, stream>>>(Pbuf, Qbuf, Rbuf, bmp[l],
                                                  src + off, dst + off, Hacc, len);
        }
        f2bf_kernel<<<(N * 256 + 255) / 256, 256, 0, stream>>>(Hacc, h_bf, N * 256);
    }

    // ---- FFN2: out = x + h@W_ff2 + b (fp32 out) ----
    gemm_kernel<<<gN, 256, 0, stream>>>(h_bf, 0, N, 256, Bp_ff2, b_ff2, x,
                                        nullptr, (float*)d_out, 0);
}

// Round 3
// 940.095 us; speedup vs baseline: 1.0444x; 1.0444x over previous
//
#include <hip/hip_runtime.h>

// ---------------------------------------------------------------------------
// ResBlock GNN layer on MI355X (gfx950). ALL tensors fp32.
//   h  = gelu(x @ W_ff1 + b)
//   h += seg_sum(gelu(P[src]+Q[dst]+R_e+b_mp)), P=h@Wa, Q=h@Wb, R=ef@Wc  (x2)
//   out = x + h @ W_ff2 + b
// R3: edges counting-sorted by dst; R-GEMM fused into the edge kernel (MFMA
// over ef), run-reduction over sorted dst rows before atomicAdd (82M -> ~23M).
// ---------------------------------------------------------------------------

typedef __attribute__((ext_vector_type(8))) short short8;
typedef __attribute__((ext_vector_type(4))) float f32x4;

#define HD __device__ __forceinline__

HD unsigned short f2bf(float f) {
    unsigned int u = __float_as_uint(f);
    return (unsigned short)((u + 0x7fffu + ((u >> 16) & 1u)) >> 16);  // RNE
}
HD float gelu_f(float x) {
    float t = tanhf(0.7978845608028654f * (x + 0.044715f * x * x * x));
    return 0.5f * x * (1.0f + t);
}

// ---------------------------------------------------------------------------
// Repack fp32 B [K,256] (from row rowoff) into bf16 MFMA B-frag order:
// Bp[((kb*16+nt)*64+lane)*8+j] = bf16(B[kb*32+(lane>>4)*8+j][nt*16+(lane&15)])
// ---------------------------------------------------------------------------
__global__ void repack_kernel(const float* __restrict__ B, int rowoff,
                              int K, unsigned short* __restrict__ Bp) {
    int i = blockIdx.x * 256 + threadIdx.x;
    if (i >= K * 256) return;
    int k = i >> 8, n = i & 255;
    int kb = k >> 5, kr = k & 31;
    int quad = kr >> 3, j = kr & 7;
    int lane = quad * 16 + (n & 15);
    int nt = n >> 4;
    Bp[((((kb * 16 + nt) * 64) + lane) << 3) + j] =
        f2bf(B[(size_t)(rowoff + k) * 256 + n]);
}

// ---------------------------------------------------------------------------
// LDS-free bf16 MFMA GEMM (64x64 tile, grid (ceil(M/64),4)), fp32 epilogue.
// ---------------------------------------------------------------------------
__global__ __launch_bounds__(256) void gemm_kernel(
    const void* __restrict__ Av, int a_is_f32, int M, int K,
    const unsigned short* __restrict__ Bp,
    const float* __restrict__ bias, const float* __restrict__ resid,
    unsigned short* __restrict__ Cb, float* __restrict__ Cf, int do_gelu) {
    int lane = threadIdx.x & 63;
    int w = threadIdx.x >> 6;
    int row0 = blockIdx.x * 64 + w * 16;
    int n0 = blockIdx.y * 64;
    int m15 = lane & 15, quad = lane >> 4;

    int arow = row0 + m15;
    if (arow > M - 1) arow = M - 1;

    f32x4 acc[4] = {{0,0,0,0},{0,0,0,0},{0,0,0,0},{0,0,0,0}};
    const float* Af = (const float*)Av + (size_t)arow * K + quad * 8;
    const unsigned short* Ab = (const unsigned short*)Av + (size_t)arow * K + quad * 8;

    for (int kt = 0; kt < K; kt += 32) {
        short8 a;
        if (a_is_f32) {
            f32x4 lo = *(const f32x4*)(Af + kt);
            f32x4 hi = *(const f32x4*)(Af + kt + 4);
#pragma unroll
            for (int j = 0; j < 4; ++j) {
                a[j] = (short)f2bf(lo[j]);
                a[j + 4] = (short)f2bf(hi[j]);
            }
        } else {
            a = *(const short8*)(Ab + kt);
        }
        const unsigned short* bbase =
            Bp + ((((size_t)(kt >> 5) * 16 + (n0 >> 4)) * 64 + lane) << 3);
#pragma unroll
        for (int nt = 0; nt < 4; ++nt) {
            short8 b = *(const short8*)(bbase + nt * 64 * 8);
            acc[nt] = __builtin_amdgcn_mfma_f32_16x16x32_bf16(a, b, acc[nt], 0, 0, 0);
        }
    }

#pragma unroll
    for (int nt = 0; nt < 4; ++nt) {
        int col = n0 + nt * 16 + m15;
        float bv = bias ? bias[col] : 0.f;
#pragma unroll
        for (int r = 0; r < 4; ++r) {
            int row = row0 + quad * 4 + r;
            if (row < M) {
                float v = acc[nt][r] + bv;
                if (do_gelu) v = gelu_f(v);
                size_t idx = (size_t)row * 256 + col;
                if (resid) v += resid[idx];
                if (Cb) Cb[idx] = f2bf(v);
                if (Cf) Cf[idx] = v;
            }
        }
    }
}

// ---------------------------------------------------------------------------
// Counting sort by dst: zero -> histogram -> single-block scan -> scatter.
// ---------------------------------------------------------------------------
__global__ void zero_i32(int* __restrict__ p, int n) {
    int i = blockIdx.x * 256 + threadIdx.x;
    if (i < n) p[i] = 0;
}
__global__ void hist_kernel(const int* __restrict__ dst, int* __restrict__ cnt, int E) {
    int e = blockIdx.x * 256 + threadIdx.x;
    if (e < E) atomicAdd(&cnt[dst[e]], 1);
}
// exclusive scan of cnt[0..N) into cursor[0..N); single block of 1024.
__global__ __launch_bounds__(1024) void scan_kernel(const int* __restrict__ cnt,
                                                    int* __restrict__ cursor, int N) {
    __shared__ int part[1024];
    int tid = threadIdx.x;
    int per = (N + 1023) / 1024;
    int lo = tid * per;
    int s = 0;
    for (int j = 0; j < per; ++j) {
        int idx = lo + j;
        if (idx < N) s += cnt[idx];
    }
    part[tid] = s;
    __syncthreads();
    for (int off = 1; off < 1024; off <<= 1) {
        int t = (tid >= off) ? part[tid - off] : 0;
        __syncthreads();
        part[tid] += t;
        __syncthreads();
    }
    int run = (tid > 0) ? part[tid - 1] : 0;
    for (int j = 0; j < per; ++j) {
        int idx = lo + j;
        if (idx < N) {
            cursor[idx] = run;
            run += cnt[idx];
        }
    }
}
__global__ void scatter_kernel(const int* __restrict__ dst, int* __restrict__ cursor,
                               int* __restrict__ perm, int E) {
    int e = blockIdx.x * 256 + threadIdx.x;
    if (e < E) {
        int pos = atomicAdd(&cursor[dst[e]], 1);
        perm[pos] = e;
    }
}

// ---------------------------------------------------------------------------
// Fused edge kernel. Block = 256 thr = 4 waves; wave handles 16 sorted edges
// x all 256 cols. R = ef[perm]@Wc via MFMA (K=64); epilogue gathers P/Q,
// bias+gelu, reduces runs of equal dst over its 4 acc rows, atomicAdd per run.
// ---------------------------------------------------------------------------
__global__ __launch_bounds__(256) void fused_edge_kernel(
    const float* __restrict__ P, const float* __restrict__ Q,
    const float* __restrict__ ef, const unsigned short* __restrict__ BpC,
    const float* __restrict__ bmp, const int* __restrict__ src,
    const int* __restrict__ dst, const int* __restrict__ perm,
    float* __restrict__ Hacc, int nE) {
    int lane = threadIdx.x & 63;
    int w = threadIdx.x >> 6;
    int base = blockIdx.x * 64 + w * 16;
    if (base >= nE) return;
    int m15 = lane & 15, quad = lane >> 4;

    int rA = base + m15;
    if (rA > nE - 1) rA = nE - 1;
    const float* Arow = ef + (size_t)perm[rA] * 64 + quad * 8;

    f32x4 acc[16];
#pragma unroll
    for (int i = 0; i < 16; ++i) acc[i] = {0.f, 0.f, 0.f, 0.f};

#pragma unroll
    for (int kb = 0; kb < 2; ++kb) {
        f32x4 lo = *(const f32x4*)(Arow + kb * 32);
        f32x4 hi = *(const f32x4*)(Arow + kb * 32 + 4);
        short8 a;
#pragma unroll
        for (int j = 0; j < 4; ++j) {
            a[j] = (short)f2bf(lo[j]);
            a[j + 4] = (short)f2bf(hi[j]);
        }
        const unsigned short* bb = BpC + (((size_t)kb * 16 * 64 + lane) << 3);
#pragma unroll
        for (int nt = 0; nt < 16; ++nt) {
            short8 b = *(const short8*)(bb + (size_t)nt * 64 * 8);
            acc[nt] = __builtin_amdgcn_mfma_f32_16x16x32_bf16(a, b, acc[nt], 0, 0, 0);
        }
    }

    int dr[4], sr[4], valid[4];
#pragma unroll
    for (int r = 0; r < 4; ++r) {
        int rr = base + quad * 4 + r;
        valid[r] = rr < nE;
        int e = perm[valid[r] ? rr : nE - 1];
        dr[r] = dst[e];
        sr[r] = src[e];
    }

#pragma unroll
    for (int nt = 0; nt < 16; ++nt) {
        int col = nt * 16 + m15;
        float bv = bmp[col];
        float run = 0.f;
#pragma unroll
        for (int r = 0; r < 4; ++r) {
            if (valid[r]) {
                float v = acc[nt][r] + P[(size_t)sr[r] * 256 + col] +
                          Q[(size_t)dr[r] * 256 + col] + bv;
                run += gelu_f(v);
                bool flush = (r == 3) || (!valid[r + 1]) || (dr[r + 1] != dr[r]);
                if (flush) {
                    atomicAdd(&Hacc[(size_t)dr[r] * 256 + col], run);
                    run = 0.f;
                }
            }
        }
    }
}

__global__ void f2bf_kernel(const float* __restrict__ in,
                            unsigned short* __restrict__ out, int n) {
    int i = blockIdx.x * 256 + threadIdx.x;
    if (i < n) out[i] = f2bf(in[i]);
}

// ---------------------------------------------------------------------------
extern "C" void kernel_launch(void* const* d_in, const int* in_sizes, int n_in,
                              void* d_out, int out_size, void* d_ws, size_t ws_size,
                              hipStream_t stream) {
    const float* x     = (const float*)d_in[0];
    const int*   ei    = (const int*)d_in[1];
    const float* ef    = (const float*)d_in[2];
    const float* W_ff1 = (const float*)d_in[3];
    const float* b_ff1 = (const float*)d_in[4];
    const float* W_mp1 = (const float*)d_in[5];
    const float* b_mp1 = (const float*)d_in[6];
    const float* W_mp2 = (const float*)d_in[7];
    const float* b_mp2 = (const float*)d_in[8];
    const float* W_ff2 = (const float*)d_in[9];
    const float* b_ff2 = (const float*)d_in[10];

    const int N = in_sizes[0] / 256;  // 10000
    const int E = in_sizes[1] / 2;    // 320000
    const int* src = ei;
    const int* dst = ei + E;

    // ---- workspace carve (256B-aligned bumps) ----
    char* p = (char*)d_ws;
    unsigned short* h_bf = (unsigned short*)p;  p += ((size_t)N * 256 * 2 + 255) & ~255ull;
    float* Pbuf = (float*)p;                    p += ((size_t)N * 256 * 4 + 255) & ~255ull;
    float* Qbuf = (float*)p;                    p += ((size_t)N * 256 * 4 + 255) & ~255ull;
    float* Hacc = (float*)p;                    p += ((size_t)N * 256 * 4 + 255) & ~255ull;
    unsigned short* Bp = (unsigned short*)p;    p += (425984ull * 2 + 255) & ~255ull;
    int* cnt    = (int*)p;                      p += ((size_t)N * 4 + 255) & ~255ull;
    int* cursor = (int*)p;                      p += ((size_t)N * 4 + 255) & ~255ull;
    int* perm   = (int*)p;                      p += ((size_t)E * 4 + 255) & ~255ull;

    unsigned short* Bp_ff1 = Bp + 0;
    unsigned short* Bp_a1  = Bp + 65536;
    unsigned short* Bp_b1  = Bp + 131072;
    unsigned short* Bp_c1  = Bp + 196608;
    unsigned short* Bp_a2  = Bp + 212992;
    unsigned short* Bp_b2  = Bp + 278528;
    unsigned short* Bp_c2  = Bp + 344064;
    unsigned short* Bp_ff2 = Bp + 360448;

    // ---- repack weights ----
    repack_kernel<<<256, 256, 0, stream>>>(W_ff1, 0, 256, Bp_ff1);
    repack_kernel<<<256, 256, 0, stream>>>(W_mp1, 0, 256, Bp_a1);
    repack_kernel<<<256, 256, 0, stream>>>(W_mp1, 256, 256, Bp_b1);
    repack_kernel<<<64, 256, 0, stream>>>(W_mp1, 512, 64, Bp_c1);
    repack_kernel<<<256, 256, 0, stream>>>(W_mp2, 0, 256, Bp_a2);
    repack_kernel<<<256, 256, 0, stream>>>(W_mp2, 256, 256, Bp_b2);
    repack_kernel<<<64, 256, 0, stream>>>(W_mp2, 512, 64, Bp_c2);
    repack_kernel<<<256, 256, 0, stream>>>(W_ff2, 0, 256, Bp_ff2);

    // ---- counting sort of edges by dst ----
    zero_i32<<<(N + 255) / 256, 256, 0, stream>>>(cnt, N);
    hist_kernel<<<(E + 255) / 256, 256, 0, stream>>>(dst, cnt, E);
    scan_kernel<<<1, 1024, 0, stream>>>(cnt, cursor, N);
    scatter_kernel<<<(E + 255) / 256, 256, 0, stream>>>(dst, cursor, perm, E);

    dim3 gN((N + 63) / 64, 4);

    // ---- FFN1: h = gelu(x@W_ff1 + b); h_bf for GEMMs, Hacc = residual base
    gemm_kernel<<<gN, 256, 0, stream>>>(x, 1, N, 256, Bp_ff1, b_ff1, nullptr,
                                        h_bf, Hacc, 1);

    const unsigned short* Bp_a[2] = {Bp_a1, Bp_a2};
    const unsigned short* Bp_b[2] = {Bp_b1, Bp_b2};
    const unsigned short* Bp_c[2] = {Bp_c1, Bp_c2};
    const float* bmp[2] = {b_mp1, b_mp2};

    for (int l = 0; l < 2; ++l) {
        gemm_kernel<<<gN, 256, 0, stream>>>(h_bf, 0, N, 256, Bp_a[l], nullptr,
                                            nullptr, nullptr, Pbuf, 0);
        gemm_kernel<<<gN, 256, 0, stream>>>(h_bf, 0, N, 256, Bp_b[l], nullptr,
                                            nullptr, nullptr, Qbuf, 0);
        fused_edge_kernel<<<(E + 63) / 64, 256, 0, stream>>>(
            Pbuf, Qbuf, ef, Bp_c[l], bmp[l], src, dst, perm, Hacc, E);
        f2bf_kernel<<<(N * 256 + 255) / 256, 256, 0, stream>>>(Hacc, h_bf, N * 256);
    }

    // ---- FFN2: out = x + h@W_ff2 + b ----
    gemm_kernel<<<gN, 256, 0, stream>>>(h_bf, 0, N, 256, Bp_ff2, b_ff2, x,
                                        nullptr, (float*)d_out, 0);
}

// Round 4
// 638.837 us; speedup vs baseline: 1.5368x; 1.4716x over previous
//
#include <hip/hip_runtime.h>

// ---------------------------------------------------------------------------
// ResBlock GNN layer on MI355X (gfx950). ALL tensors fp32.
//   h  = gelu(x @ W_ff1 + b)
//   h += seg_sum(gelu(P[src]+Q[dst]+R_e+b_mp)), P=h@Wa, Q=h@Wb, R=ef@Wc  (x2)
//   out = x + h @ W_ff2 + b
// R4: CSR no-atomic aggregation. Edges counting-sorted by dst; R materialized
// in sorted order via perm-gather MFMA GEMM (bf16); node-centric kernel
// (block=node, thread=channel) accumulates gelu messages in registers with a
// single store. P/Q stored bf16 to halve gather traffic. No atomics.
// ---------------------------------------------------------------------------

typedef __attribute__((ext_vector_type(8))) short short8;
typedef __attribute__((ext_vector_type(4))) float f32x4;

#define HD __device__ __forceinline__

HD unsigned short f2bf(float f) {
    unsigned int u = __float_as_uint(f);
    return (unsigned short)((u + 0x7fffu + ((u >> 16) & 1u)) >> 16);  // RNE
}
HD float bf2f(unsigned short u) {
    return __uint_as_float(((unsigned int)u) << 16);
}
// gelu tanh-approx via sigmoid identity: 0.5(1+tanh(z)) == sigmoid(2z).
// Safe at extremes: exp->inf gives x/inf -> +-0; exp->0 gives x.
HD float gelu_f(float x) {
    float z2 = 1.5957691216057308f * (x + 0.044715f * x * x * x);
    return x / (1.f + __expf(-z2));
}

// ---------------------------------------------------------------------------
// Repack fp32 B [K,256] (from row rowoff) into bf16 MFMA B-frag order:
// Bp[((kb*16+nt)*64+lane)*8+j] = bf16(B[kb*32+(lane>>4)*8+j][nt*16+(lane&15)])
// ---------------------------------------------------------------------------
__global__ void repack_kernel(const float* __restrict__ B, int rowoff,
                              int K, unsigned short* __restrict__ Bp) {
    int i = blockIdx.x * 256 + threadIdx.x;
    if (i >= K * 256) return;
    int k = i >> 8, n = i & 255;
    int kb = k >> 5, kr = k & 31;
    int quad = kr >> 3, j = kr & 7;
    int lane = quad * 16 + (n & 15);
    int nt = n >> 4;
    Bp[((((kb * 16 + nt) * 64) + lane) << 3) + j] =
        f2bf(B[(size_t)(rowoff + k) * 256 + n]);
}

// ---------------------------------------------------------------------------
// LDS-free bf16 MFMA GEMM (64x64 tile, grid (ceil(M/64),4)), fp32 epilogue.
// Optional row-gather via perm (A row = perm[row]); C written at local row.
// ---------------------------------------------------------------------------
__global__ __launch_bounds__(256) void gemm_kernel(
    const void* __restrict__ Av, int a_is_f32, int M, int K,
    const unsigned short* __restrict__ Bp,
    const float* __restrict__ bias, const float* __restrict__ resid,
    unsigned short* __restrict__ Cb, float* __restrict__ Cf, int do_gelu,
    const int* __restrict__ perm) {
    int lane = threadIdx.x & 63;
    int w = threadIdx.x >> 6;
    int row0 = blockIdx.x * 64 + w * 16;
    int n0 = blockIdx.y * 64;
    int m15 = lane & 15, quad = lane >> 4;

    int arow = row0 + m15;
    if (arow > M - 1) arow = M - 1;
    int grow = perm ? perm[arow] : arow;

    f32x4 acc[4] = {{0,0,0,0},{0,0,0,0},{0,0,0,0},{0,0,0,0}};
    const float* Af = (const float*)Av + (size_t)grow * K + quad * 8;
    const unsigned short* Ab = (const unsigned short*)Av + (size_t)grow * K + quad * 8;

    for (int kt = 0; kt < K; kt += 32) {
        short8 a;
        if (a_is_f32) {
            f32x4 lo = *(const f32x4*)(Af + kt);
            f32x4 hi = *(const f32x4*)(Af + kt + 4);
#pragma unroll
            for (int j = 0; j < 4; ++j) {
                a[j] = (short)f2bf(lo[j]);
                a[j + 4] = (short)f2bf(hi[j]);
            }
        } else {
            a = *(const short8*)(Ab + kt);
        }
        const unsigned short* bbase =
            Bp + ((((size_t)(kt >> 5) * 16 + (n0 >> 4)) * 64 + lane) << 3);
#pragma unroll
        for (int nt = 0; nt < 4; ++nt) {
            short8 b = *(const short8*)(bbase + nt * 64 * 8);
            acc[nt] = __builtin_amdgcn_mfma_f32_16x16x32_bf16(a, b, acc[nt], 0, 0, 0);
        }
    }

#pragma unroll
    for (int nt = 0; nt < 4; ++nt) {
        int col = n0 + nt * 16 + m15;
        float bv = bias ? bias[col] : 0.f;
#pragma unroll
        for (int r = 0; r < 4; ++r) {
            int row = row0 + quad * 4 + r;
            if (row < M) {
                float v = acc[nt][r] + bv;
                if (do_gelu) v = gelu_f(v);
                size_t idx = (size_t)row * 256 + col;
                if (resid) v += resid[idx];
                if (Cb) Cb[idx] = f2bf(v);
                if (Cf) Cf[idx] = v;
            }
        }
    }
}

// ---------------------------------------------------------------------------
// Counting sort by dst: zero -> histogram -> single-block scan -> scatter.
// After scatter, cursor[d] = end offset; start = cursor[d] - cnt[d].
// ---------------------------------------------------------------------------
__global__ void zero_i32(int* __restrict__ p, int n) {
    int i = blockIdx.x * 256 + threadIdx.x;
    if (i < n) p[i] = 0;
}
__global__ void hist_kernel(const int* __restrict__ dst, int* __restrict__ cnt, int E) {
    int e = blockIdx.x * 256 + threadIdx.x;
    if (e < E) atomicAdd(&cnt[dst[e]], 1);
}
__global__ __launch_bounds__(1024) void scan_kernel(const int* __restrict__ cnt,
                                                    int* __restrict__ cursor, int N) {
    __shared__ int part[1024];
    int tid = threadIdx.x;
    int per = (N + 1023) / 1024;
    int lo = tid * per;
    int s = 0;
    for (int j = 0; j < per; ++j) {
        int idx = lo + j;
        if (idx < N) s += cnt[idx];
    }
    part[tid] = s;
    __syncthreads();
    for (int off = 1; off < 1024; off <<= 1) {
        int t = (tid >= off) ? part[tid - off] : 0;
        __syncthreads();
        part[tid] += t;
        __syncthreads();
    }
    int run = (tid > 0) ? part[tid - 1] : 0;
    for (int j = 0; j < per; ++j) {
        int idx = lo + j;
        if (idx < N) {
            cursor[idx] = run;
            run += cnt[idx];
        }
    }
}
__global__ void scatter_kernel(const int* __restrict__ src, const int* __restrict__ dst,
                               int* __restrict__ cursor, int* __restrict__ perm,
                               int* __restrict__ srcs, int E) {
    int e = blockIdx.x * 256 + threadIdx.x;
    if (e < E) {
        int pos = atomicAdd(&cursor[dst[e]], 1);
        perm[pos] = e;
        srcs[pos] = src[e];
    }
}

// ---------------------------------------------------------------------------
// Node kernel: block = node d, thread = channel c. CSR edges [beg,end) clamped
// to window [off, off+len); acc = Hacc[d][c] + sum gelu(P[s]+Q[d]+R[i]+b).
// No atomics; single store. h_bf written on the final window.
// ---------------------------------------------------------------------------
__global__ __launch_bounds__(256) void node_kernel(
    const unsigned short* __restrict__ Pb, const unsigned short* __restrict__ Qb,
    const unsigned short* __restrict__ Rbuf, const float* __restrict__ bmp,
    const int* __restrict__ srcs, const int* __restrict__ cursor,
    const int* __restrict__ cnt, float* __restrict__ Hacc,
    unsigned short* __restrict__ h_bf, int off, int len, int is_last) {
    __shared__ int s_src[256];
    int d = blockIdx.x;
    int c = threadIdx.x;
    int end = cursor[d];
    int beg = end - cnt[d];
    if (beg < off) beg = off;
    if (end > off + len) end = off + len;

    size_t nidx = (size_t)d * 256 + c;
    float acc = Hacc[nidx];

    if (beg < end) {
        float q = bf2f(Qb[nidx]) + bmp[c];
        for (int base = beg; base < end; base += 256) {
            int m = end - base;
            if (m > 256) m = 256;
            __syncthreads();
            if (c < m) s_src[c] = srcs[base + c];
            __syncthreads();
#pragma unroll 4
            for (int j = 0; j < m; ++j) {
                int s = s_src[j];
                float v = bf2f(Pb[(size_t)s * 256 + c]) + q +
                          bf2f(Rbuf[(size_t)(base - off + j) * 256 + c]);
                acc += gelu_f(v);
            }
        }
        Hacc[nidx] = acc;
    }
    if (is_last) h_bf[nidx] = f2bf(acc);
}

// ---------------------------------------------------------------------------
extern "C" void kernel_launch(void* const* d_in, const int* in_sizes, int n_in,
                              void* d_out, int out_size, void* d_ws, size_t ws_size,
                              hipStream_t stream) {
    const float* x     = (const float*)d_in[0];
    const int*   ei    = (const int*)d_in[1];
    const float* ef    = (const float*)d_in[2];
    const float* W_ff1 = (const float*)d_in[3];
    const float* b_ff1 = (const float*)d_in[4];
    const float* W_mp1 = (const float*)d_in[5];
    const float* b_mp1 = (const float*)d_in[6];
    const float* W_mp2 = (const float*)d_in[7];
    const float* b_mp2 = (const float*)d_in[8];
    const float* W_ff2 = (const float*)d_in[9];
    const float* b_ff2 = (const float*)d_in[10];

    const int N = in_sizes[0] / 256;  // 10000
    const int E = in_sizes[1] / 2;    // 320000
    const int* src = ei;
    const int* dst = ei + E;

    // ---- workspace carve (256B-aligned bumps) ----
    char* p = (char*)d_ws;
    unsigned short* h_bf = (unsigned short*)p;  p += ((size_t)N * 256 * 2 + 255) & ~255ull;
    unsigned short* Pbuf = (unsigned short*)p;  p += ((size_t)N * 256 * 2 + 255) & ~255ull;
    unsigned short* Qbuf = (unsigned short*)p;  p += ((size_t)N * 256 * 2 + 255) & ~255ull;
    float* Hacc = (float*)p;                    p += ((size_t)N * 256 * 4 + 255) & ~255ull;
    unsigned short* Bp = (unsigned short*)p;    p += (425984ull * 2 + 255) & ~255ull;
    int* cnt    = (int*)p;                      p += ((size_t)N * 4 + 255) & ~255ull;
    int* cursor = (int*)p;                      p += ((size_t)N * 4 + 255) & ~255ull;
    int* perm   = (int*)p;                      p += ((size_t)E * 4 + 255) & ~255ull;
    int* srcs   = (int*)p;                      p += ((size_t)E * 4 + 255) & ~255ull;
    unsigned short* Rbuf = (unsigned short*)p;  // bf16, chunked

    long long remain = (long long)ws_size - (long long)(p - (char*)d_ws);
    long long chunk = remain / 512;  // 256 bf16 per edge row
    chunk -= (chunk % 64);
    if (chunk > E) chunk = E;
    if (chunk < 64) chunk = 64;

    unsigned short* Bp_ff1 = Bp + 0;
    unsigned short* Bp_a1  = Bp + 65536;
    unsigned short* Bp_b1  = Bp + 131072;
    unsigned short* Bp_c1  = Bp + 196608;
    unsigned short* Bp_a2  = Bp + 212992;
    unsigned short* Bp_b2  = Bp + 278528;
    unsigned short* Bp_c2  = Bp + 344064;
    unsigned short* Bp_ff2 = Bp + 360448;

    // ---- repack weights ----
    repack_kernel<<<256, 256, 0, stream>>>(W_ff1, 0, 256, Bp_ff1);
    repack_kernel<<<256, 256, 0, stream>>>(W_mp1, 0, 256, Bp_a1);
    repack_kernel<<<256, 256, 0, stream>>>(W_mp1, 256, 256, Bp_b1);
    repack_kernel<<<64, 256, 0, stream>>>(W_mp1, 512, 64, Bp_c1);
    repack_kernel<<<256, 256, 0, stream>>>(W_mp2, 0, 256, Bp_a2);
    repack_kernel<<<256, 256, 0, stream>>>(W_mp2, 256, 256, Bp_b2);
    repack_kernel<<<64, 256, 0, stream>>>(W_mp2, 512, 64, Bp_c2);
    repack_kernel<<<256, 256, 0, stream>>>(W_ff2, 0, 256, Bp_ff2);

    // ---- counting sort of edges by dst (CSR) ----
    zero_i32<<<(N + 255) / 256, 256, 0, stream>>>(cnt, N);
    hist_kernel<<<(E + 255) / 256, 256, 0, stream>>>(dst, cnt, E);
    scan_kernel<<<1, 1024, 0, stream>>>(cnt, cursor, N);
    scatter_kernel<<<(E + 255) / 256, 256, 0, stream>>>(src, dst, cursor, perm, srcs, E);

    dim3 gN((N + 63) / 64, 4);

    // ---- FFN1: h = gelu(x@W_ff1 + b); h_bf for GEMMs, Hacc = residual base
    gemm_kernel<<<gN, 256, 0, stream>>>(x, 1, N, 256, Bp_ff1, b_ff1, nullptr,
                                        h_bf, Hacc, 1, nullptr);

    const unsigned short* Bp_a[2] = {Bp_a1, Bp_a2};
    const unsigned short* Bp_b[2] = {Bp_b1, Bp_b2};
    const unsigned short* Bp_c[2] = {Bp_c1, Bp_c2};
    const float* bmp[2] = {b_mp1, b_mp2};

    for (int l = 0; l < 2; ++l) {
        gemm_kernel<<<gN, 256, 0, stream>>>(h_bf, 0, N, 256, Bp_a[l], nullptr,
                                            nullptr, Pbuf, nullptr, 0, nullptr);
        gemm_kernel<<<gN, 256, 0, stream>>>(h_bf, 0, N, 256, Bp_b[l], nullptr,
                                            nullptr, Qbuf, nullptr, 0, nullptr);
        for (long long off = 0; off < E; off += chunk) {
            int len = (int)((E - off < chunk) ? (E - off) : chunk);
            int last = (off + len >= E);
            dim3 gR(((len + 63) / 64), 4);
            gemm_kernel<<<gR, 256, 0, stream>>>(ef, 1, len, 64, Bp_c[l], nullptr,
                                                nullptr, Rbuf, nullptr, 0,
                                                perm + off);
            node_kernel<<<N, 256, 0, stream>>>(Pbuf, Qbuf, Rbuf, bmp[l], srcs,
                                               cursor, cnt, Hacc, h_bf,
                                               (int)off, len, last);
        }
    }

    // ---- FFN2: out = x + h@W_ff2 + b ----
    gemm_kernel<<<gN, 256, 0, stream>>>(h_bf, 0, N, 256, Bp_ff2, b_ff2, x,
                                        nullptr, (float*)d_out, 0, nullptr);
}

// Round 5
// 634.238 us; speedup vs baseline: 1.5480x; 1.0073x over previous
//
#include <hip/hip_runtime.h>

// ---------------------------------------------------------------------------
// ResBlock GNN layer on MI355X (gfx950). ALL tensors fp32.
//   h  = gelu(x @ W_ff1 + b)
//   h += seg_sum(gelu(P[src]+Q[dst]+R_e+b_mp)), P=h@Wa, Q=h@Wb, R=ef@Wc  (x2)
//   out = x + h @ W_ff2 + b
// R5: R computed in ORIGINAL edge order (sequential coalesced ef reads, no
// gather in the GEMM); node kernel reads Rbuf[perm[j]] -- scattered 512B rows,
// block-coalesced, zero overfetch. CSR no-atomic aggregation as in R4.
// ---------------------------------------------------------------------------

typedef __attribute__((ext_vector_type(8))) short short8;
typedef __attribute__((ext_vector_type(4))) float f32x4;

#define HD __device__ __forceinline__

HD unsigned short f2bf(float f) {
    unsigned int u = __float_as_uint(f);
    return (unsigned short)((u + 0x7fffu + ((u >> 16) & 1u)) >> 16);  // RNE
}
HD float bf2f(unsigned short u) {
    return __uint_as_float(((unsigned int)u) << 16);
}
// gelu tanh-approx via sigmoid identity: 0.5(1+tanh(z)) == sigmoid(2z).
HD float gelu_f(float x) {
    float z2 = 1.5957691216057308f * (x + 0.044715f * x * x * x);
    return x / (1.f + __expf(-z2));
}

// ---------------------------------------------------------------------------
// Repack fp32 B [K,256] (from row rowoff) into bf16 MFMA B-frag order.
// ---------------------------------------------------------------------------
__global__ void repack_kernel(const float* __restrict__ B, int rowoff,
                              int K, unsigned short* __restrict__ Bp) {
    int i = blockIdx.x * 256 + threadIdx.x;
    if (i >= K * 256) return;
    int k = i >> 8, n = i & 255;
    int kb = k >> 5, kr = k & 31;
    int quad = kr >> 3, j = kr & 7;
    int lane = quad * 16 + (n & 15);
    int nt = n >> 4;
    Bp[((((kb * 16 + nt) * 64) + lane) << 3) + j] =
        f2bf(B[(size_t)(rowoff + k) * 256 + n]);
}

// ---------------------------------------------------------------------------
// LDS-free bf16 MFMA GEMM (64x64 tile, grid (ceil(M/64),4)), fp32 epilogue.
// Optional row-gather via perm (fallback path only).
// ---------------------------------------------------------------------------
__global__ __launch_bounds__(256) void gemm_kernel(
    const void* __restrict__ Av, int a_is_f32, int M, int K,
    const unsigned short* __restrict__ Bp,
    const float* __restrict__ bias, const float* __restrict__ resid,
    unsigned short* __restrict__ Cb, float* __restrict__ Cf, int do_gelu,
    const int* __restrict__ perm) {
    int lane = threadIdx.x & 63;
    int w = threadIdx.x >> 6;
    int row0 = blockIdx.x * 64 + w * 16;
    int n0 = blockIdx.y * 64;
    int m15 = lane & 15, quad = lane >> 4;

    int arow = row0 + m15;
    if (arow > M - 1) arow = M - 1;
    int grow = perm ? perm[arow] : arow;

    f32x4 acc[4] = {{0,0,0,0},{0,0,0,0},{0,0,0,0},{0,0,0,0}};
    const float* Af = (const float*)Av + (size_t)grow * K + quad * 8;
    const unsigned short* Ab = (const unsigned short*)Av + (size_t)grow * K + quad * 8;

    for (int kt = 0; kt < K; kt += 32) {
        short8 a;
        if (a_is_f32) {
            f32x4 lo = *(const f32x4*)(Af + kt);
            f32x4 hi = *(const f32x4*)(Af + kt + 4);
#pragma unroll
            for (int j = 0; j < 4; ++j) {
                a[j] = (short)f2bf(lo[j]);
                a[j + 4] = (short)f2bf(hi[j]);
            }
        } else {
            a = *(const short8*)(Ab + kt);
        }
        const unsigned short* bbase =
            Bp + ((((size_t)(kt >> 5) * 16 + (n0 >> 4)) * 64 + lane) << 3);
#pragma unroll
        for (int nt = 0; nt < 4; ++nt) {
            short8 b = *(const short8*)(bbase + nt * 64 * 8);
            acc[nt] = __builtin_amdgcn_mfma_f32_16x16x32_bf16(a, b, acc[nt], 0, 0, 0);
        }
    }

#pragma unroll
    for (int nt = 0; nt < 4; ++nt) {
        int col = n0 + nt * 16 + m15;
        float bv = bias ? bias[col] : 0.f;
#pragma unroll
        for (int r = 0; r < 4; ++r) {
            int row = row0 + quad * 4 + r;
            if (row < M) {
                float v = acc[nt][r] + bv;
                if (do_gelu) v = gelu_f(v);
                size_t idx = (size_t)row * 256 + col;
                if (resid) v += resid[idx];
                if (Cb) Cb[idx] = f2bf(v);
                if (Cf) Cf[idx] = v;
            }
        }
    }
}

// ---------------------------------------------------------------------------
// Counting sort by dst: zero -> histogram -> single-block scan -> scatter.
// After scatter, cursor[d] = end offset; start = cursor[d] - cnt[d].
// ---------------------------------------------------------------------------
__global__ void zero_i32(int* __restrict__ p, int n) {
    int i = blockIdx.x * 256 + threadIdx.x;
    if (i < n) p[i] = 0;
}
__global__ void hist_kernel(const int* __restrict__ dst, int* __restrict__ cnt, int E) {
    int e = blockIdx.x * 256 + threadIdx.x;
    if (e < E) atomicAdd(&cnt[dst[e]], 1);
}
__global__ __launch_bounds__(1024) void scan_kernel(const int* __restrict__ cnt,
                                                    int* __restrict__ cursor, int N) {
    __shared__ int part[1024];
    int tid = threadIdx.x;
    int per = (N + 1023) / 1024;
    int lo = tid * per;
    int s = 0;
    for (int j = 0; j < per; ++j) {
        int idx = lo + j;
        if (idx < N) s += cnt[idx];
    }
    part[tid] = s;
    __syncthreads();
    for (int off = 1; off < 1024; off <<= 1) {
        int t = (tid >= off) ? part[tid - off] : 0;
        __syncthreads();
        part[tid] += t;
        __syncthreads();
    }
    int run = (tid > 0) ? part[tid - 1] : 0;
    for (int j = 0; j < per; ++j) {
        int idx = lo + j;
        if (idx < N) {
            cursor[idx] = run;
            run += cnt[idx];
        }
    }
}
__global__ void scatter_kernel(const int* __restrict__ src, const int* __restrict__ dst,
                               int* __restrict__ cursor, int* __restrict__ perm,
                               int* __restrict__ srcs, int E) {
    int e = blockIdx.x * 256 + threadIdx.x;
    if (e < E) {
        int pos = atomicAdd(&cursor[dst[e]], 1);
        perm[pos] = e;
        srcs[pos] = src[e];
    }
}

// ---------------------------------------------------------------------------
// Node kernel: block = node d, thread = channel c. CSR positions [beg,end)
// clamped to window [off, off+len). acc = Hacc[d] + sum gelu(P[s]+Q[d]+R+b).
// r_orig=1: Rbuf indexed by ORIGINAL edge id (perm[pos]); else by pos-off.
// No atomics; one store. store_f32 gates the Hacc write (skip on last layer).
// ---------------------------------------------------------------------------
__global__ __launch_bounds__(256) void node_kernel(
    const unsigned short* __restrict__ Pb, const unsigned short* __restrict__ Qb,
    const unsigned short* __restrict__ Rbuf, const float* __restrict__ bmp,
    const int* __restrict__ srcs, const int* __restrict__ perm,
    const int* __restrict__ cursor, const int* __restrict__ cnt,
    float* __restrict__ Hacc, unsigned short* __restrict__ h_bf,
    int off, int len, int r_orig, int store_f32, int is_last) {
    __shared__ int s_src[256];
    __shared__ int s_eid[256];
    int d = blockIdx.x;
    int c = threadIdx.x;
    int end = cursor[d];
    int beg = end - cnt[d];
    if (beg < off) beg = off;
    if (end > off + len) end = off + len;

    size_t nidx = (size_t)d * 256 + c;
    float acc = Hacc[nidx];

    if (beg < end) {
        float q = bf2f(Qb[nidx]) + bmp[c];
        for (int base = beg; base < end; base += 256) {
            int m = end - base;
            if (m > 256) m = 256;
            __syncthreads();
            if (c < m) {
                s_src[c] = srcs[base + c];
                s_eid[c] = r_orig ? perm[base + c] : (base - off + c);
            }
            __syncthreads();
#pragma unroll 4
            for (int j = 0; j < m; ++j) {
                int s = s_src[j];
                float v = bf2f(Pb[(size_t)s * 256 + c]) + q +
                          bf2f(Rbuf[(size_t)s_eid[j] * 256 + c]);
                acc += gelu_f(v);
            }
        }
        if (store_f32) Hacc[nidx] = acc;
    }
    if (is_last) h_bf[nidx] = f2bf(acc);
}

// ---------------------------------------------------------------------------
extern "C" void kernel_launch(void* const* d_in, const int* in_sizes, int n_in,
                              void* d_out, int out_size, void* d_ws, size_t ws_size,
                              hipStream_t stream) {
    const float* x     = (const float*)d_in[0];
    const int*   ei    = (const int*)d_in[1];
    const float* ef    = (const float*)d_in[2];
    const float* W_ff1 = (const float*)d_in[3];
    const float* b_ff1 = (const float*)d_in[4];
    const float* W_mp1 = (const float*)d_in[5];
    const float* b_mp1 = (const float*)d_in[6];
    const float* W_mp2 = (const float*)d_in[7];
    const float* b_mp2 = (const float*)d_in[8];
    const float* W_ff2 = (const float*)d_in[9];
    const float* b_ff2 = (const float*)d_in[10];

    const int N = in_sizes[0] / 256;  // 10000
    const int E = in_sizes[1] / 2;    // 320000
    const int* src = ei;
    const int* dst = ei + E;

    // ---- workspace carve (256B-aligned bumps) ----
    char* p = (char*)d_ws;
    unsigned short* h_bf = (unsigned short*)p;  p += ((size_t)N * 256 * 2 + 255) & ~255ull;
    unsigned short* Pbuf = (unsigned short*)p;  p += ((size_t)N * 256 * 2 + 255) & ~255ull;
    unsigned short* Qbuf = (unsigned short*)p;  p += ((size_t)N * 256 * 2 + 255) & ~255ull;
    float* Hacc = (float*)p;                    p += ((size_t)N * 256 * 4 + 255) & ~255ull;
    unsigned short* Bp = (unsigned short*)p;    p += (425984ull * 2 + 255) & ~255ull;
    int* cnt    = (int*)p;                      p += ((size_t)N * 4 + 255) & ~255ull;
    int* cursor = (int*)p;                      p += ((size_t)N * 4 + 255) & ~255ull;
    int* perm   = (int*)p;                      p += ((size_t)E * 4 + 255) & ~255ull;
    int* srcs   = (int*)p;                      p += ((size_t)E * 4 + 255) & ~255ull;
    unsigned short* Rbuf = (unsigned short*)p;  // bf16

    long long remain = (long long)ws_size - (long long)(p - (char*)d_ws);
    long long chunk = remain / 512;  // 256 bf16 per edge row
    chunk -= (chunk % 64);
    if (chunk > E) chunk = E;
    if (chunk < 64) chunk = 64;
    int full = (chunk >= E);

    unsigned short* Bp_ff1 = Bp + 0;
    unsigned short* Bp_a1  = Bp + 65536;
    unsigned short* Bp_b1  = Bp + 131072;
    unsigned short* Bp_c1  = Bp + 196608;
    unsigned short* Bp_a2  = Bp + 212992;
    unsigned short* Bp_b2  = Bp + 278528;
    unsigned short* Bp_c2  = Bp + 344064;
    unsigned short* Bp_ff2 = Bp + 360448;

    // ---- repack weights ----
    repack_kernel<<<256, 256, 0, stream>>>(W_ff1, 0, 256, Bp_ff1);
    repack_kernel<<<256, 256, 0, stream>>>(W_mp1, 0, 256, Bp_a1);
    repack_kernel<<<256, 256, 0, stream>>>(W_mp1, 256, 256, Bp_b1);
    repack_kernel<<<64, 256, 0, stream>>>(W_mp1, 512, 64, Bp_c1);
    repack_kernel<<<256, 256, 0, stream>>>(W_mp2, 0, 256, Bp_a2);
    repack_kernel<<<256, 256, 0, stream>>>(W_mp2, 256, 256, Bp_b2);
    repack_kernel<<<64, 256, 0, stream>>>(W_mp2, 512, 64, Bp_c2);
    repack_kernel<<<256, 256, 0, stream>>>(W_ff2, 0, 256, Bp_ff2);

    // ---- counting sort of edges by dst (CSR) ----
    zero_i32<<<(N + 255) / 256, 256, 0, stream>>>(cnt, N);
    hist_kernel<<<(E + 255) / 256, 256, 0, stream>>>(dst, cnt, E);
    scan_kernel<<<1, 1024, 0, stream>>>(cnt, cursor, N);
    scatter_kernel<<<(E + 255) / 256, 256, 0, stream>>>(src, dst, cursor, perm, srcs, E);

    dim3 gN((N + 63) / 64, 4);

    // ---- FFN1: h = gelu(x@W_ff1 + b); h_bf for GEMMs, Hacc = residual base
    gemm_kernel<<<gN, 256, 0, stream>>>(x, 1, N, 256, Bp_ff1, b_ff1, nullptr,
                                        h_bf, Hacc, 1, nullptr);

    const unsigned short* Bp_a[2] = {Bp_a1, Bp_a2};
    const unsigned short* Bp_b[2] = {Bp_b1, Bp_b2};
    const unsigned short* Bp_c[2] = {Bp_c1, Bp_c2};
    const float* bmp[2] = {b_mp1, b_mp2};

    for (int l = 0; l < 2; ++l) {
        gemm_kernel<<<gN, 256, 0, stream>>>(h_bf, 0, N, 256, Bp_a[l], nullptr,
                                            nullptr, Pbuf, nullptr, 0, nullptr);
        gemm_kernel<<<gN, 256, 0, stream>>>(h_bf, 0, N, 256, Bp_b[l], nullptr,
                                            nullptr, Qbuf, nullptr, 0, nullptr);
        if (full) {
            // R in original edge order: sequential ef reads, no gather.
            dim3 gR((E + 63) / 64, 4);
            gemm_kernel<<<gR, 256, 0, stream>>>(ef, 1, E, 64, Bp_c[l], nullptr,
                                                nullptr, Rbuf, nullptr, 0, nullptr);
            node_kernel<<<N, 256, 0, stream>>>(Pbuf, Qbuf, Rbuf, bmp[l], srcs,
                                               perm, cursor, cnt, Hacc, h_bf,
                                               0, E, 1, l == 0, 1);
        } else {
            // fallback: chunked perm-gather (R4 behavior)
            for (long long off = 0; off < E; off += chunk) {
                int len = (int)((E - off < chunk) ? (E - off) : chunk);
                int last = (off + len >= E);
                dim3 gR(((len + 63) / 64), 4);
                gemm_kernel<<<gR, 256, 0, stream>>>(ef, 1, len, 64, Bp_c[l],
                                                    nullptr, nullptr, Rbuf,
                                                    nullptr, 0, perm + off);
                node_kernel<<<N, 256, 0, stream>>>(Pbuf, Qbuf, Rbuf, bmp[l], srcs,
                                                   perm, cursor, cnt, Hacc, h_bf,
                                                   (int)off, len, 0, 1, last);
            }
        }
    }

    // ---- FFN2: out = x + h@W_ff2 + b ----
    gemm_kernel<<<gN, 256, 0, stream>>>(h_bf, 0, N, 256, Bp_ff2, b_ff2, x,
                                        nullptr, (float*)d_out, 0, nullptr);
}

// Round 6
// 534.849 us; speedup vs baseline: 1.8357x; 1.1858x over previous
//
#include <hip/hip_runtime.h>

// ---------------------------------------------------------------------------
// ResBlock GNN layer on MI355X (gfx950). ALL tensors fp32.
//   h  = gelu(x @ W_ff1 + b)
//   h += seg_sum(gelu(P[src]+Q[dst]+R_e+b_mp)), P=h@Wa, Q=h@Wb, R=ef@Wc  (x2)
//   out = x + h @ W_ff2 + b
// R6: dedicated rgemm_kernel for R = ef@Wc (original edge order): one block =
// 64 rows x 256 cols (A read once), LDS-staged bf16 tile -> full-line uint4
// stores (kills the ~80 MB write-allocate RMW traffic seen in R5 counters).
// CSR no-atomic node aggregation unchanged.
// ---------------------------------------------------------------------------

typedef __attribute__((ext_vector_type(8))) short short8;
typedef __attribute__((ext_vector_type(4))) float f32x4;

#define HD __device__ __forceinline__

HD unsigned short f2bf(float f) {
    unsigned int u = __float_as_uint(f);
    return (unsigned short)((u + 0x7fffu + ((u >> 16) & 1u)) >> 16);  // RNE
}
HD float bf2f(unsigned short u) {
    return __uint_as_float(((unsigned int)u) << 16);
}
// gelu tanh-approx via sigmoid identity: 0.5(1+tanh(z)) == sigmoid(2z).
HD float gelu_f(float x) {
    float z2 = 1.5957691216057308f * (x + 0.044715f * x * x * x);
    return x / (1.f + __expf(-z2));
}

// ---------------------------------------------------------------------------
// Repack fp32 B [K,256] (from row rowoff) into bf16 MFMA B-frag order.
// ---------------------------------------------------------------------------
__global__ void repack_kernel(const float* __restrict__ B, int rowoff,
                              int K, unsigned short* __restrict__ Bp) {
    int i = blockIdx.x * 256 + threadIdx.x;
    if (i >= K * 256) return;
    int k = i >> 8, n = i & 255;
    int kb = k >> 5, kr = k & 31;
    int quad = kr >> 3, j = kr & 7;
    int lane = quad * 16 + (n & 15);
    int nt = n >> 4;
    Bp[((((kb * 16 + nt) * 64) + lane) << 3) + j] =
        f2bf(B[(size_t)(rowoff + k) * 256 + n]);
}

// ---------------------------------------------------------------------------
// General LDS-free bf16 MFMA GEMM (64x64 tile, grid (ceil(M/64),4)).
// ---------------------------------------------------------------------------
__global__ __launch_bounds__(256) void gemm_kernel(
    const void* __restrict__ Av, int a_is_f32, int M, int K,
    const unsigned short* __restrict__ Bp,
    const float* __restrict__ bias, const float* __restrict__ resid,
    unsigned short* __restrict__ Cb, float* __restrict__ Cf, int do_gelu,
    const int* __restrict__ perm) {
    int lane = threadIdx.x & 63;
    int w = threadIdx.x >> 6;
    int row0 = blockIdx.x * 64 + w * 16;
    int n0 = blockIdx.y * 64;
    int m15 = lane & 15, quad = lane >> 4;

    int arow = row0 + m15;
    if (arow > M - 1) arow = M - 1;
    int grow = perm ? perm[arow] : arow;

    f32x4 acc[4] = {{0,0,0,0},{0,0,0,0},{0,0,0,0},{0,0,0,0}};
    const float* Af = (const float*)Av + (size_t)grow * K + quad * 8;
    const unsigned short* Ab = (const unsigned short*)Av + (size_t)grow * K + quad * 8;

    for (int kt = 0; kt < K; kt += 32) {
        short8 a;
        if (a_is_f32) {
            f32x4 lo = *(const f32x4*)(Af + kt);
            f32x4 hi = *(const f32x4*)(Af + kt + 4);
#pragma unroll
            for (int j = 0; j < 4; ++j) {
                a[j] = (short)f2bf(lo[j]);
                a[j + 4] = (short)f2bf(hi[j]);
            }
        } else {
            a = *(const short8*)(Ab + kt);
        }
        const unsigned short* bbase =
            Bp + ((((size_t)(kt >> 5) * 16 + (n0 >> 4)) * 64 + lane) << 3);
#pragma unroll
        for (int nt = 0; nt < 4; ++nt) {
            short8 b = *(const short8*)(bbase + nt * 64 * 8);
            acc[nt] = __builtin_amdgcn_mfma_f32_16x16x32_bf16(a, b, acc[nt], 0, 0, 0);
        }
    }

#pragma unroll
    for (int nt = 0; nt < 4; ++nt) {
        int col = n0 + nt * 16 + m15;
        float bv = bias ? bias[col] : 0.f;
#pragma unroll
        for (int r = 0; r < 4; ++r) {
            int row = row0 + quad * 4 + r;
            if (row < M) {
                float v = acc[nt][r] + bv;
                if (do_gelu) v = gelu_f(v);
                size_t idx = (size_t)row * 256 + col;
                if (resid) v += resid[idx];
                if (Cb) Cb[idx] = f2bf(v);
                if (Cf) Cf[idx] = v;
            }
        }
    }
}

// ---------------------------------------------------------------------------
// Dedicated R-GEMM: Rout[M,256](bf16) = A[M,64](fp32) @ Wc (pre-packed).
// Block = 64 rows x 256 cols (4 waves x 16 rows); A read once per block.
// Epilogue: stage tile in LDS, bulk uint4 stores (full-line, coalesced).
// ---------------------------------------------------------------------------
__global__ __launch_bounds__(256) void rgemm_kernel(
    const float* __restrict__ A, int M,
    const unsigned short* __restrict__ BpC,
    unsigned short* __restrict__ Rout) {
    __shared__ unsigned short tile[64 * 256];  // 32 KB
    int lane = threadIdx.x & 63;
    int w = threadIdx.x >> 6;
    int m15 = lane & 15, quad = lane >> 4;
    int row0 = blockIdx.x * 64;

    int arow = row0 + w * 16 + m15;
    if (arow > M - 1) arow = M - 1;
    const float* Af = A + (size_t)arow * 64 + quad * 8;

    f32x4 acc[16];
#pragma unroll
    for (int i = 0; i < 16; ++i) acc[i] = {0.f, 0.f, 0.f, 0.f};

#pragma unroll
    for (int kb = 0; kb < 2; ++kb) {
        f32x4 lo = *(const f32x4*)(Af + kb * 32);
        f32x4 hi = *(const f32x4*)(Af + kb * 32 + 4);
        short8 a;
#pragma unroll
        for (int j = 0; j < 4; ++j) {
            a[j] = (short)f2bf(lo[j]);
            a[j + 4] = (short)f2bf(hi[j]);
        }
        const unsigned short* bb = BpC + (((size_t)kb * 16 * 64 + lane) << 3);
#pragma unroll
        for (int nt = 0; nt < 16; ++nt) {
            short8 b = *(const short8*)(bb + (size_t)nt * 64 * 8);
            acc[nt] = __builtin_amdgcn_mfma_f32_16x16x32_bf16(a, b, acc[nt], 0, 0, 0);
        }
    }

    // stage into LDS at [local_row][col]
#pragma unroll
    for (int nt = 0; nt < 16; ++nt) {
        int col = nt * 16 + m15;
#pragma unroll
        for (int r = 0; r < 4; ++r) {
            int lrow = w * 16 + quad * 4 + r;
            tile[lrow * 256 + col] = f2bf(acc[nt][r]);
        }
    }
    __syncthreads();

    // bulk store: 2048 uint4; thread t writes idx = i*256 + t (lane-consecutive)
    int rows_left = M - row0;  // may exceed 64; clamp via lrow check
    const uint4* tsrc = (const uint4*)tile;
    uint4* gdst = (uint4*)(Rout + (size_t)row0 * 256);
#pragma unroll
    for (int i = 0; i < 8; ++i) {
        int idx = i * 256 + threadIdx.x;
        int lrow = idx >> 5;  // 32 uint4 per 512B row
        if (lrow < rows_left) gdst[idx] = tsrc[idx];
    }
}

// ---------------------------------------------------------------------------
// Counting sort by dst: zero -> histogram -> single-block scan -> scatter.
// ---------------------------------------------------------------------------
__global__ void zero_i32(int* __restrict__ p, int n) {
    int i = blockIdx.x * 256 + threadIdx.x;
    if (i < n) p[i] = 0;
}
__global__ void hist_kernel(const int* __restrict__ dst, int* __restrict__ cnt, int E) {
    int e = blockIdx.x * 256 + threadIdx.x;
    if (e < E) atomicAdd(&cnt[dst[e]], 1);
}
__global__ __launch_bounds__(1024) void scan_kernel(const int* __restrict__ cnt,
                                                    int* __restrict__ cursor, int N) {
    __shared__ int part[1024];
    int tid = threadIdx.x;
    int per = (N + 1023) / 1024;
    int lo = tid * per;
    int s = 0;
    for (int j = 0; j < per; ++j) {
        int idx = lo + j;
        if (idx < N) s += cnt[idx];
    }
    part[tid] = s;
    __syncthreads();
    for (int off = 1; off < 1024; off <<= 1) {
        int t = (tid >= off) ? part[tid - off] : 0;
        __syncthreads();
        part[tid] += t;
        __syncthreads();
    }
    int run = (tid > 0) ? part[tid - 1] : 0;
    for (int j = 0; j < per; ++j) {
        int idx = lo + j;
        if (idx < N) {
            cursor[idx] = run;
            run += cnt[idx];
        }
    }
}
__global__ void scatter_kernel(const int* __restrict__ src, const int* __restrict__ dst,
                               int* __restrict__ cursor, int* __restrict__ perm,
                               int* __restrict__ srcs, int E) {
    int e = blockIdx.x * 256 + threadIdx.x;
    if (e < E) {
        int pos = atomicAdd(&cursor[dst[e]], 1);
        perm[pos] = e;
        srcs[pos] = src[e];
    }
}

// ---------------------------------------------------------------------------
// Node kernel: block = node d, thread = channel c. CSR positions [beg,end)
// clamped to window [off, off+len). acc = Hacc[d] + sum gelu(P[s]+Q[d]+R+b).
// r_orig=1: Rbuf indexed by original edge id (perm[pos]); else pos-off.
// ---------------------------------------------------------------------------
__global__ __launch_bounds__(256) void node_kernel(
    const unsigned short* __restrict__ Pb, const unsigned short* __restrict__ Qb,
    const unsigned short* __restrict__ Rbuf, const float* __restrict__ bmp,
    const int* __restrict__ srcs, const int* __restrict__ perm,
    const int* __restrict__ cursor, const int* __restrict__ cnt,
    float* __restrict__ Hacc, unsigned short* __restrict__ h_bf,
    int off, int len, int r_orig, int store_f32, int is_last) {
    __shared__ int s_src[256];
    __shared__ int s_eid[256];
    int d = blockIdx.x;
    int c = threadIdx.x;
    int end = cursor[d];
    int beg = end - cnt[d];
    if (beg < off) beg = off;
    if (end > off + len) end = off + len;

    size_t nidx = (size_t)d * 256 + c;
    float acc = Hacc[nidx];

    if (beg < end) {
        float q = bf2f(Qb[nidx]) + bmp[c];
        for (int base = beg; base < end; base += 256) {
            int m = end - base;
            if (m > 256) m = 256;
            __syncthreads();
            if (c < m) {
                s_src[c] = srcs[base + c];
                s_eid[c] = r_orig ? perm[base + c] : (base - off + c);
            }
            __syncthreads();
#pragma unroll 4
            for (int j = 0; j < m; ++j) {
                int s = s_src[j];
                float v = bf2f(Pb[(size_t)s * 256 + c]) + q +
                          bf2f(Rbuf[(size_t)s_eid[j] * 256 + c]);
                acc += gelu_f(v);
            }
        }
        if (store_f32) Hacc[nidx] = acc;
    }
    if (is_last) h_bf[nidx] = f2bf(acc);
}

// ---------------------------------------------------------------------------
extern "C" void kernel_launch(void* const* d_in, const int* in_sizes, int n_in,
                              void* d_out, int out_size, void* d_ws, size_t ws_size,
                              hipStream_t stream) {
    const float* x     = (const float*)d_in[0];
    const int*   ei    = (const int*)d_in[1];
    const float* ef    = (const float*)d_in[2];
    const float* W_ff1 = (const float*)d_in[3];
    const float* b_ff1 = (const float*)d_in[4];
    const float* W_mp1 = (const float*)d_in[5];
    const float* b_mp1 = (const float*)d_in[6];
    const float* W_mp2 = (const float*)d_in[7];
    const float* b_mp2 = (const float*)d_in[8];
    const float* W_ff2 = (const float*)d_in[9];
    const float* b_ff2 = (const float*)d_in[10];

    const int N = in_sizes[0] / 256;  // 10000
    const int E = in_sizes[1] / 2;    // 320000
    const int* src = ei;
    const int* dst = ei + E;

    // ---- workspace carve (256B-aligned bumps) ----
    char* p = (char*)d_ws;
    unsigned short* h_bf = (unsigned short*)p;  p += ((size_t)N * 256 * 2 + 255) & ~255ull;
    unsigned short* Pbuf = (unsigned short*)p;  p += ((size_t)N * 256 * 2 + 255) & ~255ull;
    unsigned short* Qbuf = (unsigned short*)p;  p += ((size_t)N * 256 * 2 + 255) & ~255ull;
    float* Hacc = (float*)p;                    p += ((size_t)N * 256 * 4 + 255) & ~255ull;
    unsigned short* Bp = (unsigned short*)p;    p += (425984ull * 2 + 255) & ~255ull;
    int* cnt    = (int*)p;                      p += ((size_t)N * 4 + 255) & ~255ull;
    int* cursor = (int*)p;                      p += ((size_t)N * 4 + 255) & ~255ull;
    int* perm   = (int*)p;                      p += ((size_t)E * 4 + 255) & ~255ull;
    int* srcs   = (int*)p;                      p += ((size_t)E * 4 + 255) & ~255ull;
    unsigned short* Rbuf = (unsigned short*)p;  // bf16

    long long remain = (long long)ws_size - (long long)(p - (char*)d_ws);
    long long chunk = remain / 512;  // 256 bf16 per edge row
    chunk -= (chunk % 64);
    if (chunk > E) chunk = E;
    if (chunk < 64) chunk = 64;
    int full = (chunk >= E);

    unsigned short* Bp_ff1 = Bp + 0;
    unsigned short* Bp_a1  = Bp + 65536;
    unsigned short* Bp_b1  = Bp + 131072;
    unsigned short* Bp_c1  = Bp + 196608;
    unsigned short* Bp_a2  = Bp + 212992;
    unsigned short* Bp_b2  = Bp + 278528;
    unsigned short* Bp_c2  = Bp + 344064;
    unsigned short* Bp_ff2 = Bp + 360448;

    // ---- repack weights ----
    repack_kernel<<<256, 256, 0, stream>>>(W_ff1, 0, 256, Bp_ff1);
    repack_kernel<<<256, 256, 0, stream>>>(W_mp1, 0, 256, Bp_a1);
    repack_kernel<<<256, 256, 0, stream>>>(W_mp1, 256, 256, Bp_b1);
    repack_kernel<<<64, 256, 0, stream>>>(W_mp1, 512, 64, Bp_c1);
    repack_kernel<<<256, 256, 0, stream>>>(W_mp2, 0, 256, Bp_a2);
    repack_kernel<<<256, 256, 0, stream>>>(W_mp2, 256, 256, Bp_b2);
    repack_kernel<<<64, 256, 0, stream>>>(W_mp2, 512, 64, Bp_c2);
    repack_kernel<<<256, 256, 0, stream>>>(W_ff2, 0, 256, Bp_ff2);

    // ---- counting sort of edges by dst (CSR) ----
    zero_i32<<<(N + 255) / 256, 256, 0, stream>>>(cnt, N);
    hist_kernel<<<(E + 255) / 256, 256, 0, stream>>>(dst, cnt, E);
    scan_kernel<<<1, 1024, 0, stream>>>(cnt, cursor, N);
    scatter_kernel<<<(E + 255) / 256, 256, 0, stream>>>(src, dst, cursor, perm, srcs, E);

    dim3 gN((N + 63) / 64, 4);

    // ---- FFN1: h = gelu(x@W_ff1 + b); h_bf for GEMMs, Hacc = residual base
    gemm_kernel<<<gN, 256, 0, stream>>>(x, 1, N, 256, Bp_ff1, b_ff1, nullptr,
                                        h_bf, Hacc, 1, nullptr);

    const unsigned short* Bp_a[2] = {Bp_a1, Bp_a2};
    const unsigned short* Bp_b[2] = {Bp_b1, Bp_b2};
    const unsigned short* Bp_c[2] = {Bp_c1, Bp_c2};
    const float* bmp[2] = {b_mp1, b_mp2};

    for (int l = 0; l < 2; ++l) {
        gemm_kernel<<<gN, 256, 0, stream>>>(h_bf, 0, N, 256, Bp_a[l], nullptr,
                                            nullptr, Pbuf, nullptr, 0, nullptr);
        gemm_kernel<<<gN, 256, 0, stream>>>(h_bf, 0, N, 256, Bp_b[l], nullptr,
                                            nullptr, Qbuf, nullptr, 0, nullptr);
        if (full) {
            // R in original edge order: sequential reads, LDS-staged stores.
            rgemm_kernel<<<(E + 63) / 64, 256, 0, stream>>>(ef, E, Bp_c[l], Rbuf);
            node_kernel<<<N, 256, 0, stream>>>(Pbuf, Qbuf, Rbuf, bmp[l], srcs,
                                               perm, cursor, cnt, Hacc, h_bf,
                                               0, E, 1, l == 0, 1);
        } else {
            // fallback: chunked perm-gather (R4 behavior)
            for (long long off = 0; off < E; off += chunk) {
                int len = (int)((E - off < chunk) ? (E - off) : chunk);
                int last = (off + len >= E);
                dim3 gR(((len + 63) / 64), 4);
                gemm_kernel<<<gR, 256, 0, stream>>>(ef, 1, len, 64, Bp_c[l],
                                                    nullptr, nullptr, Rbuf,
                                                    nullptr, 0, perm + off);
                node_kernel<<<N, 256, 0, stream>>>(Pbuf, Qbuf, Rbuf, bmp[l], srcs,
                                                   perm, cursor, cnt, Hacc, h_bf,
                                                   (int)off, len, 0, 1, last);
            }
        }
    }

    // ---- FFN2: out = x + h@W_ff2 + b ----
    gemm_kernel<<<gN, 256, 0, stream>>>(h_bf, 0, N, 256, Bp_ff2, b_ff2, x,
                                        nullptr, (float*)d_out, 0, nullptr);
}

// Round 7
// 534.017 us; speedup vs baseline: 1.8385x; 1.0016x over previous
//
#include <hip/hip_runtime.h>

// ---------------------------------------------------------------------------
// ResBlock GNN layer on MI355X (gfx950). ALL tensors fp32.
//   h  = gelu(x @ W_ff1 + b)
//   h += seg_sum(gelu(P[src]+Q[dst]+R_e+b_mp)), P=h@Wa, Q=h@Wb, R=ef@Wc  (x2)
//   out = x + h @ W_ff2 + b
// R7: rgemm perm-gathers ef so Rbuf is in SORTED (CSR) order -> node reads R
// sequentially. node_kernel: wave-per-node, 4ch/thread uint2 loads, scalar
// (readfirstlane) addressing, rcp-based gelu (no div chain), no LDS/barriers.
// Q-GEMM folds b_mp. P+Q in one dispatch; all weight repacks in one dispatch.
// ---------------------------------------------------------------------------

typedef __attribute__((ext_vector_type(8))) short short8;
typedef __attribute__((ext_vector_type(4))) float f32x4;

#define HD __device__ __forceinline__

HD unsigned short f2bf(float f) {
    unsigned int u = __float_as_uint(f);
    return (unsigned short)((u + 0x7fffu + ((u >> 16) & 1u)) >> 16);  // RNE
}
HD float lo16(unsigned int u) { return __uint_as_float(u << 16); }
HD float hi16(unsigned int u) { return __uint_as_float(u & 0xffff0000u); }
HD float bf2f(unsigned short u) { return __uint_as_float(((unsigned int)u) << 16); }

// gelu tanh-approx via sigmoid identity: 0.5(1+tanh(z)) == sigmoid(2z).
// u = -(a1*x + a1*c*x^3);  gelu = x * rcp(1 + exp(u))   (v_rcp, no div chain)
HD float gelu_f(float x) {
    float u = x * (-1.5957691216057308f - 0.07135481627f * (x * x));
    return x * __builtin_amdgcn_rcpf(1.f + __expf(u));
}

// ---------------------------------------------------------------------------
// All 8 weight repacks in one dispatch. Segment boundaries are multiples of
// 256 elems, so each block maps to exactly one segment.
// ---------------------------------------------------------------------------
__global__ void repack_all(const float* __restrict__ Wff1,
                           const float* __restrict__ Wmp1,
                           const float* __restrict__ Wmp2,
                           const float* __restrict__ Wff2,
                           unsigned short* __restrict__ Bp) {
    const int begs[9] = {0, 65536, 131072, 196608, 212992, 278528, 344064,
                         360448, 425984};
    const int srcid[8] = {0, 1, 1, 1, 2, 2, 2, 3};
    const int rowoff[8] = {0, 0, 256, 512, 0, 256, 512, 0};
    int i = blockIdx.x * 256 + threadIdx.x;
    if (i >= 425984) return;
    int s = 0;
#pragma unroll
    for (int k = 1; k < 8; ++k)
        if (i >= begs[k]) s = k;
    const float* Ws[4] = {Wff1, Wmp1, Wmp2, Wff2};
    const float* B = Ws[srcid[s]];
    int local = i - begs[s];
    int k = local >> 8, n = local & 255;
    int kb = k >> 5, kr = k & 31;
    int quad = kr >> 3, j = kr & 7;
    int lane = quad * 16 + (n & 15);
    int nt = n >> 4;
    Bp[begs[s] + ((((kb * 16 + nt) * 64) + lane) << 3) + j] =
        f2bf(B[(size_t)(rowoff[s] + k) * 256 + n]);
}

// ---------------------------------------------------------------------------
// General LDS-free bf16 MFMA GEMM (64x64 tile, grid (ceil(M/64),4)) for FFNs.
// ---------------------------------------------------------------------------
__global__ __launch_bounds__(256) void gemm_kernel(
    const void* __restrict__ Av, int a_is_f32, int M, int K,
    const unsigned short* __restrict__ Bp,
    const float* __restrict__ bias, const float* __restrict__ resid,
    unsigned short* __restrict__ Cb, float* __restrict__ Cf, int do_gelu) {
    int lane = threadIdx.x & 63;
    int w = threadIdx.x >> 6;
    int row0 = blockIdx.x * 64 + w * 16;
    int n0 = blockIdx.y * 64;
    int m15 = lane & 15, quad = lane >> 4;

    int arow = row0 + m15;
    if (arow > M - 1) arow = M - 1;

    f32x4 acc[4] = {{0,0,0,0},{0,0,0,0},{0,0,0,0},{0,0,0,0}};
    const float* Af = (const float*)Av + (size_t)arow * K + quad * 8;
    const unsigned short* Ab = (const unsigned short*)Av + (size_t)arow * K + quad * 8;

    for (int kt = 0; kt < K; kt += 32) {
        short8 a;
        if (a_is_f32) {
            f32x4 lo = *(const f32x4*)(Af + kt);
            f32x4 hi = *(const f32x4*)(Af + kt + 4);
#pragma unroll
            for (int j = 0; j < 4; ++j) {
                a[j] = (short)f2bf(lo[j]);
                a[j + 4] = (short)f2bf(hi[j]);
            }
        } else {
            a = *(const short8*)(Ab + kt);
        }
        const unsigned short* bbase =
            Bp + ((((size_t)(kt >> 5) * 16 + (n0 >> 4)) * 64 + lane) << 3);
#pragma unroll
        for (int nt = 0; nt < 4; ++nt) {
            short8 b = *(const short8*)(bbase + nt * 64 * 8);
            acc[nt] = __builtin_amdgcn_mfma_f32_16x16x32_bf16(a, b, acc[nt], 0, 0, 0);
        }
    }

#pragma unroll
    for (int nt = 0; nt < 4; ++nt) {
        int col = n0 + nt * 16 + m15;
        float bv = bias ? bias[col] : 0.f;
#pragma unroll
        for (int r = 0; r < 4; ++r) {
            int row = row0 + quad * 4 + r;
            if (row < M) {
                float v = acc[nt][r] + bv;
                if (do_gelu) v = gelu_f(v);
                size_t idx = (size_t)row * 256 + col;
                if (resid) v += resid[idx];
                if (Cb) Cb[idx] = f2bf(v);
                if (Cf) Cf[idx] = v;
            }
        }
    }
}

// ---------------------------------------------------------------------------
// P and Q in one dispatch: grid ((M+63)/64, 8); y<4 -> P cols, y>=4 -> Q cols.
// Q folds b_mp into the epilogue.
// ---------------------------------------------------------------------------
__global__ __launch_bounds__(256) void pq_kernel(
    const unsigned short* __restrict__ A, int M,
    const unsigned short* __restrict__ BpA, const unsigned short* __restrict__ BpB,
    const float* __restrict__ qbias,
    unsigned short* __restrict__ Pb, unsigned short* __restrict__ Qb) {
    int lane = threadIdx.x & 63;
    int w = threadIdx.x >> 6;
    int row0 = blockIdx.x * 64 + w * 16;
    int isQ = blockIdx.y >> 2;
    int n0 = (blockIdx.y & 3) * 64;
    const unsigned short* Bp = isQ ? BpB : BpA;
    unsigned short* out = isQ ? Qb : Pb;
    int m15 = lane & 15, quad = lane >> 4;

    int arow = row0 + m15;
    if (arow > M - 1) arow = M - 1;
    const unsigned short* Ab = A + (size_t)arow * 256 + quad * 8;

    f32x4 acc[4] = {{0,0,0,0},{0,0,0,0},{0,0,0,0},{0,0,0,0}};
    for (int kt = 0; kt < 256; kt += 32) {
        short8 a = *(const short8*)(Ab + kt);
        const unsigned short* bbase =
            Bp + ((((size_t)(kt >> 5) * 16 + (n0 >> 4)) * 64 + lane) << 3);
#pragma unroll
        for (int nt = 0; nt < 4; ++nt) {
            short8 b = *(const short8*)(bbase + nt * 64 * 8);
            acc[nt] = __builtin_amdgcn_mfma_f32_16x16x32_bf16(a, b, acc[nt], 0, 0, 0);
        }
    }

#pragma unroll
    for (int nt = 0; nt < 4; ++nt) {
        int col = n0 + nt * 16 + m15;
        float bv = isQ ? qbias[col] : 0.f;
#pragma unroll
        for (int r = 0; r < 4; ++r) {
            int row = row0 + quad * 4 + r;
            if (row < M) out[(size_t)row * 256 + col] = f2bf(acc[nt][r] + bv);
        }
    }
}

// ---------------------------------------------------------------------------
// R-GEMM: Rout[i] = bf16(ef[perm[i]] @ Wc), i in [0,len) -- SORTED order.
// Block = 64 rows x 256 cols; LDS-staged full-line uint4 stores.
// ---------------------------------------------------------------------------
__global__ __launch_bounds__(256) void rgemm_kernel(
    const float* __restrict__ A, const int* __restrict__ perm, int Mlen,
    const unsigned short* __restrict__ BpC, unsigned short* __restrict__ Rout) {
    __shared__ unsigned short tile[64 * 256];  // 32 KB
    int lane = threadIdx.x & 63;
    int w = threadIdx.x >> 6;
    int m15 = lane & 15, quad = lane >> 4;
    int row0 = blockIdx.x * 64;

    int arow = row0 + w * 16 + m15;
    if (arow > Mlen - 1) arow = Mlen - 1;
    int grow = perm[arow];
    const float* Af = A + (size_t)grow * 64 + quad * 8;

    f32x4 acc[16];
#pragma unroll
    for (int i = 0; i < 16; ++i) acc[i] = {0.f, 0.f, 0.f, 0.f};

#pragma unroll
    for (int kb = 0; kb < 2; ++kb) {
        f32x4 lo = *(const f32x4*)(Af + kb * 32);
        f32x4 hi = *(const f32x4*)(Af + kb * 32 + 4);
        short8 a;
#pragma unroll
        for (int j = 0; j < 4; ++j) {
            a[j] = (short)f2bf(lo[j]);
            a[j + 4] = (short)f2bf(hi[j]);
        }
        const unsigned short* bb = BpC + (((size_t)kb * 16 * 64 + lane) << 3);
#pragma unroll
        for (int nt = 0; nt < 16; ++nt) {
            short8 b = *(const short8*)(bb + (size_t)nt * 64 * 8);
            acc[nt] = __builtin_amdgcn_mfma_f32_16x16x32_bf16(a, b, acc[nt], 0, 0, 0);
        }
    }

#pragma unroll
    for (int nt = 0; nt < 16; ++nt) {
        int col = nt * 16 + m15;
#pragma unroll
        for (int r = 0; r < 4; ++r) {
            int lrow = w * 16 + quad * 4 + r;
            tile[lrow * 256 + col] = f2bf(acc[nt][r]);
        }
    }
    __syncthreads();

    int rows_left = Mlen - row0;
    const uint4* tsrc = (const uint4*)tile;
    uint4* gdst = (uint4*)(Rout + (size_t)row0 * 256);
#pragma unroll
    for (int i = 0; i < 8; ++i) {
        int idx = i * 256 + threadIdx.x;
        int lrow = idx >> 5;
        if (lrow < rows_left) gdst[idx] = tsrc[idx];
    }
}

// ---------------------------------------------------------------------------
// Counting sort by dst: zero -> histogram -> single-block scan -> scatter.
// ---------------------------------------------------------------------------
__global__ void zero_i32(int* __restrict__ p, int n) {
    int i = blockIdx.x * 256 + threadIdx.x;
    if (i < n) p[i] = 0;
}
__global__ void hist_kernel(const int* __restrict__ dst, int* __restrict__ cnt, int E) {
    int e = blockIdx.x * 256 + threadIdx.x;
    if (e < E) atomicAdd(&cnt[dst[e]], 1);
}
__global__ __launch_bounds__(1024) void scan_kernel(const int* __restrict__ cnt,
                                                    int* __restrict__ cursor, int N) {
    __shared__ int part[1024];
    int tid = threadIdx.x;
    int per = (N + 1023) / 1024;
    int lo = tid * per;
    int s = 0;
    for (int j = 0; j < per; ++j) {
        int idx = lo + j;
        if (idx < N) s += cnt[idx];
    }
    part[tid] = s;
    __syncthreads();
    for (int off = 1; off < 1024; off <<= 1) {
        int t = (tid >= off) ? part[tid - off] : 0;
        __syncthreads();
        part[tid] += t;
        __syncthreads();
    }
    int run = (tid > 0) ? part[tid - 1] : 0;
    for (int j = 0; j < per; ++j) {
        int idx = lo + j;
        if (idx < N) {
            cursor[idx] = run;
            run += cnt[idx];
        }
    }
}
__global__ void scatter_kernel(const int* __restrict__ src, const int* __restrict__ dst,
                               int* __restrict__ cursor, int* __restrict__ perm,
                               int* __restrict__ srcs, int E) {
    int e = blockIdx.x * 256 + threadIdx.x;
    if (e < E) {
        int pos = atomicAdd(&cursor[dst[e]], 1);
        perm[pos] = e;
        srcs[pos] = src[e];
    }
}

// ---------------------------------------------------------------------------
// Node kernel: wave w of block handles node d = blockIdx*4+w; lane owns 4
// channels (c0=lane*4). R sequential (sorted), P via scalar-addressed gather
// (readfirstlane), Q has bias folded. No LDS, no barriers, no atomics.
// ---------------------------------------------------------------------------
__global__ __launch_bounds__(256) void node_kernel(
    const unsigned short* __restrict__ Pb, const unsigned short* __restrict__ Qb,
    const unsigned short* __restrict__ Rbuf, const int* __restrict__ srcs,
    const int* __restrict__ cursor, const int* __restrict__ cnt,
    float* __restrict__ Hacc, unsigned short* __restrict__ h_bf,
    int N, int off, int len, int store_f32, int write_h) {
    int lane = threadIdx.x & 63;
    int w = threadIdx.x >> 6;
    int d = blockIdx.x * 4 + w;
    if (d >= N) return;
    int c0 = lane << 2;
    size_t nidx = ((size_t)d << 8) + c0;
    float4 acc = *(const float4*)(Hacc + nidx);

    int end = cursor[d];
    int beg = end - cnt[d];
    if (beg < off) beg = off;
    int e2 = end;
    if (e2 > off + len) e2 = off + len;

    if (beg < e2) {
        uint2 qu = *(const uint2*)(Qb + nidx);
        float q0 = lo16(qu.x), q1 = hi16(qu.x);
        float q2 = lo16(qu.y), q3 = hi16(qu.y);
        const unsigned short* Rrow = Rbuf + (((size_t)(beg - off)) << 8) + c0;
        int pos = beg;
        for (; pos + 8 <= e2; pos += 8, Rrow += 8 * 256) {
#pragma unroll
            for (int k = 0; k < 8; ++k) {
                int s = __builtin_amdgcn_readfirstlane(srcs[pos + k]);
                uint2 pu = *(const uint2*)(Pb + (((size_t)s) << 8) + c0);
                uint2 ru = *(const uint2*)(Rrow + (size_t)k * 256);
                float v0 = lo16(pu.x) + q0 + lo16(ru.x);
                float v1 = hi16(pu.x) + q1 + hi16(ru.x);
                float v2 = lo16(pu.y) + q2 + lo16(ru.y);
                float v3 = hi16(pu.y) + q3 + hi16(ru.y);
                acc.x += gelu_f(v0);
                acc.y += gelu_f(v1);
                acc.z += gelu_f(v2);
                acc.w += gelu_f(v3);
            }
        }
        for (; pos < e2; ++pos, Rrow += 256) {
            int s = __builtin_amdgcn_readfirstlane(srcs[pos]);
            uint2 pu = *(const uint2*)(Pb + (((size_t)s) << 8) + c0);
            uint2 ru = *(const uint2*)(Rrow);
            float v0 = lo16(pu.x) + q0 + lo16(ru.x);
            float v1 = hi16(pu.x) + q1 + hi16(ru.x);
            float v2 = lo16(pu.y) + q2 + lo16(ru.y);
            float v3 = hi16(pu.y) + q3 + hi16(ru.y);
            acc.x += gelu_f(v0);
            acc.y += gelu_f(v1);
            acc.z += gelu_f(v2);
            acc.w += gelu_f(v3);
        }
    }
    if (store_f32) *(float4*)(Hacc + nidx) = acc;
    if (write_h) {
        uint2 o;
        o.x = (unsigned int)f2bf(acc.x) | ((unsigned int)f2bf(acc.y) << 16);
        o.y = (unsigned int)f2bf(acc.z) | ((unsigned int)f2bf(acc.w) << 16);
        *(uint2*)(h_bf + nidx) = o;
    }
}

// ---------------------------------------------------------------------------
extern "C" void kernel_launch(void* const* d_in, const int* in_sizes, int n_in,
                              void* d_out, int out_size, void* d_ws, size_t ws_size,
                              hipStream_t stream) {
    const float* x     = (const float*)d_in[0];
    const int*   ei    = (const int*)d_in[1];
    const float* ef    = (const float*)d_in[2];
    const float* W_ff1 = (const float*)d_in[3];
    const float* b_ff1 = (const float*)d_in[4];
    const float* W_mp1 = (const float*)d_in[5];
    const float* b_mp1 = (const float*)d_in[6];
    const float* W_mp2 = (const float*)d_in[7];
    const float* b_mp2 = (const float*)d_in[8];
    const float* W_ff2 = (const float*)d_in[9];
    const float* b_ff2 = (const float*)d_in[10];

    const int N = in_sizes[0] / 256;  // 10000
    const int E = in_sizes[1] / 2;    // 320000
    const int* src = ei;
    const int* dst = ei + E;

    // ---- workspace carve (256B-aligned bumps) ----
    char* p = (char*)d_ws;
    unsigned short* h_bf = (unsigned short*)p;  p += ((size_t)N * 256 * 2 + 255) & ~255ull;
    unsigned short* Pbuf = (unsigned short*)p;  p += ((size_t)N * 256 * 2 + 255) & ~255ull;
    unsigned short* Qbuf = (unsigned short*)p;  p += ((size_t)N * 256 * 2 + 255) & ~255ull;
    float* Hacc = (float*)p;                    p += ((size_t)N * 256 * 4 + 255) & ~255ull;
    unsigned short* Bp = (unsigned short*)p;    p += (425984ull * 2 + 255) & ~255ull;
    int* cnt    = (int*)p;                      p += ((size_t)N * 4 + 255) & ~255ull;
    int* cursor = (int*)p;                      p += ((size_t)N * 4 + 255) & ~255ull;
    int* perm   = (int*)p;                      p += ((size_t)E * 4 + 255) & ~255ull;
    int* srcs   = (int*)p;                      p += ((size_t)E * 4 + 255) & ~255ull;
    unsigned short* Rbuf = (unsigned short*)p;  // bf16, sorted order

    long long remain = (long long)ws_size - (long long)(p - (char*)d_ws);
    long long chunk = remain / 512;  // 256 bf16 per edge row
    chunk -= (chunk % 64);
    if (chunk > E) chunk = E;
    if (chunk < 64) chunk = 64;

    unsigned short* Bp_ff1 = Bp + 0;
    unsigned short* Bp_a1  = Bp + 65536;
    unsigned short* Bp_b1  = Bp + 131072;
    unsigned short* Bp_c1  = Bp + 196608;
    unsigned short* Bp_a2  = Bp + 212992;
    unsigned short* Bp_b2  = Bp + 278528;
    unsigned short* Bp_c2  = Bp + 344064;
    unsigned short* Bp_ff2 = Bp + 360448;

    // ---- repack all weights (single dispatch) ----
    repack_all<<<1664, 256, 0, stream>>>(W_ff1, W_mp1, W_mp2, W_ff2, Bp);

    // ---- counting sort of edges by dst (CSR) ----
    zero_i32<<<(N + 255) / 256, 256, 0, stream>>>(cnt, N);
    hist_kernel<<<(E + 255) / 256, 256, 0, stream>>>(dst, cnt, E);
    scan_kernel<<<1, 1024, 0, stream>>>(cnt, cursor, N);
    scatter_kernel<<<(E + 255) / 256, 256, 0, stream>>>(src, dst, cursor, perm, srcs, E);

    dim3 gN((N + 63) / 64, 4);
    dim3 gPQ((N + 63) / 64, 8);

    // ---- FFN1: h = gelu(x@W_ff1 + b); h_bf for GEMMs, Hacc = residual base
    gemm_kernel<<<gN, 256, 0, stream>>>(x, 1, N, 256, Bp_ff1, b_ff1, nullptr,
                                        h_bf, Hacc, 1);

    const unsigned short* Bp_a[2] = {Bp_a1, Bp_a2};
    const unsigned short* Bp_b[2] = {Bp_b1, Bp_b2};
    const unsigned short* Bp_c[2] = {Bp_c1, Bp_c2};
    const float* bmp[2] = {b_mp1, b_mp2};

    for (int l = 0; l < 2; ++l) {
        pq_kernel<<<gPQ, 256, 0, stream>>>(h_bf, N, Bp_a[l], Bp_b[l], bmp[l],
                                           Pbuf, Qbuf);
        for (long long off = 0; off < E; off += chunk) {
            int len = (int)((E - off < chunk) ? (E - off) : chunk);
            int last = (off + len >= E);
            rgemm_kernel<<<(len + 63) / 64, 256, 0, stream>>>(
                ef, perm + off, len, Bp_c[l], Rbuf);
            node_kernel<<<(N + 3) / 4, 256, 0, stream>>>(
                Pbuf, Qbuf, Rbuf, srcs, cursor, cnt, Hacc, h_bf,
                N, (int)off, len, (l == 0) || !last, last);
        }
    }

    // ---- FFN2: out = x + h@W_ff2 + b ----
    gemm_kernel<<<gN, 256, 0, stream>>>(h_bf, 0, N, 256, Bp_ff2, b_ff2, x,
                                        nullptr, (float*)d_out, 0);
}